// Round 6
// baseline (186.225 us; speedup 1.0000x reference)
//
#include <hip/hip_runtime.h>
#include <hip/hip_bf16.h>

// LTAE fused implementation for gfx950.
// K1 (R6): PE sincos via full-rate polynomial (rndne + FMA Horner; no
//     quarter-rate v_sin/v_cos); P6b on waves 2-3 overlapped with all-thread
//     P7 pe-accumulation (one less serial phase). K0 bid70 split 4-way.

typedef __attribute__((ext_vector_type(8))) short bf16x8;   // 8 bf16 (4 VGPRs)
typedef __attribute__((ext_vector_type(4))) float f32x4;

#define EPS 1e-5f
#define INV_SQRT8 0.35355339059327373f
#define KDIV (-0.07785768972392256f)   /* -log2(1000)/128 */
#define INV2PI 0.15915494309189535f
#define LOG2E 1.4426950408889634f

// sin(2*pi*r)/cos(2*pi*r) minimax-ish (Chebyshev/Bessel) on r in [-0.5,0.5],
// abs err <= ~2.5e-4 (sin deg7) / ~1.3e-4 (cos deg8) -- well under bf16 ulp.
#define SA1 6.2785980f
#define SA3 -41.0922624f
#define SA5 77.9146240f
#define SA7 -56.0414720f
#define CC0 0.9999973f
#define CC2 -19.7317952f
#define CC4 64.6724864f
#define CC6 -82.3955456f
#define CC8 45.6261632f

__device__ __forceinline__ unsigned short f2bf(float f){
  union { float f; unsigned u; } v; v.f = f;
  unsigned r = v.u + 0x7FFFu + ((v.u >> 16) & 1u);   // RNE
  return (unsigned short)(r >> 16);
}
__device__ __forceinline__ float bf2f(unsigned short h){
  union { unsigned u; float f; } v; v.u = ((unsigned)h) << 16; return v.f;
}
__device__ __forceinline__ float asf(unsigned u){
  union { unsigned u; float f; } v; v.u = u; return v.f;
}
// packed RNE f32x2 -> bf16x2 (v_cvt_pk_bf16_f32 on gfx950), low short = lo
__device__ __forceinline__ unsigned pk2bf(float lo, float hi){
  __hip_bfloat162 h2 = __float22bfloat162_rn(make_float2(lo, hi));
  return *reinterpret_cast<unsigned*>(&h2);
}

// ---------------------------------------------------------------- K0: prepack
__global__ __launch_bounds__(256) void k0_pre(
    const float* __restrict__ conv_w, const float* __restrict__ conv_b,
    const float* __restrict__ bn1_g, const float* __restrict__ bn1_b,
    const float* __restrict__ bn1_m, const float* __restrict__ bn1_v,
    const float* __restrict__ Q, const float* __restrict__ Wk,
    const float* __restrict__ bk,
    const float* __restrict__ W1, const float* __restrict__ b1,
    const float* __restrict__ bn2_g, const float* __restrict__ bn2_b,
    const float* __restrict__ bn2_m, const float* __restrict__ bn2_v,
    const float* __restrict__ oln_g, const float* __restrict__ oln_b,
    const float* __restrict__ Wd1, const float* __restrict__ bd1,
    const float* __restrict__ bnd1_g, const float* __restrict__ bnd1_b,
    const float* __restrict__ bnd1_m, const float* __restrict__ bnd1_v,
    const float* __restrict__ Wd2, const float* __restrict__ bd2,
    const float* __restrict__ bnd2_g, const float* __restrict__ bnd2_b,
    const float* __restrict__ bnd2_m, const float* __restrict__ bnd2_v,
    const float* __restrict__ Wd3,
    unsigned short* __restrict__ wqF, unsigned short* __restrict__ w1F,
    unsigned short* __restrict__ wd1F, unsigned short* __restrict__ wd2F,
    unsigned short* __restrict__ wd3F,
    float* __restrict__ convwT, float* __restrict__ convbE,
    float* __restrict__ biasq, float* __restrict__ b1E,
    float* __restrict__ bd1E, float* __restrict__ bd2E)
{
  __shared__ float redL[256];
  const int t = threadIdx.x;
  const int bid = blockIdx.x;

  if (bid < 64){                               // W1F: [8nt][8kc][64][8]
    for (int e = bid*512 + t; e < bid*512 + 512; e += 256){
      int j = e & 7, lj = (e >> 3) & 63, kc = (e >> 9) & 7, nt = (e >> 12) & 7;
      int n = nt*16 + (lj & 15);
      int k = kc*32 + ((lj >> 4) << 3) + j;
      float s2 = bn2_g[n] * rsqrtf(bn2_v[n] + EPS);
      w1F[e] = f2bf(W1[n*256 + k] * s2);
    }
  } else if (bid < 68){                        // Wd1F: [4nt][4kc][64][8], oln_g folded
    int base = (bid - 64)*2048;
    #pragma unroll 4
    for (int it = 0; it < 8; ++it){
      int e = base + it*256 + t;
      int j = e & 7, lj = (e >> 3) & 63, kc = (e >> 9) & 3, nt = (e >> 11) & 3;
      int n = nt*16 + (lj & 15);
      int k = kc*32 + ((lj >> 4) << 3) + j;
      float sd = bnd1_g[n] * rsqrtf(bnd1_v[n] + EPS);
      wd1F[e] = f2bf(Wd1[n*128 + k] * sd * oln_g[k]);
    }
  } else if (bid == 68){                       // Wd2F: [2nt][2kc][64][8]
    #pragma unroll 4
    for (int it = 0; it < 8; ++it){
      int e = it*256 + t;
      int j = e & 7, lj = (e >> 3) & 63, kc = (e >> 9) & 1, nt = (e >> 10) & 1;
      int n = nt*16 + (lj & 15);
      int k = kc*32 + ((lj >> 4) << 3) + j;
      float sd = bnd2_g[n] * rsqrtf(bnd2_v[n] + EPS);
      wd2F[e] = f2bf(Wd2[n*64 + k] * sd);
    }
  } else if (bid == 69){                       // Wd3F: [2nt][64][8], zero pad n>=20
    #pragma unroll
    for (int it = 0; it < 4; ++it){
      int e = it*256 + t;
      int j = e & 7, lj = (e >> 3) & 63, nt = (e >> 9) & 1;
      int n = nt*16 + (lj & 15);
      int k = ((lj >> 4) << 3) + j;
      float v = (n < 20) ? Wd3[n*32 + k] : 0.f;
      wd3F[e] = f2bf(v);
    }
  } else if (bid == 70 || bid >= 75){          // WqF kc 0..7 (split over 4 blocks)
    int c0 = (bid == 70) ? 0 : (bid - 74)*4;   // it base: 0,4,8,12
    #pragma unroll
    for (int i2 = 0; i2 < 4; ++i2){
      int e = (c0 + i2)*256 + t;
      int j = e & 7, lj = (e >> 3) & 63, kc = (e >> 9) & 7;
      int h = lj & 15;
      int dd = kc*32 + ((lj >> 4) << 3) + j;
      float acc = 0.f;
      #pragma unroll
      for (int kk = 0; kk < 8; ++kk)
        acc += Q[h*8+kk] * Wk[(h*8+kk)*256 + dd];
      wqF[e] = f2bf(acc * INV_SQRT8);
    }
  } else if (bid == 71){                       // WqF kc=8 (conv fold A[h,c]) + biasq
    __shared__ float wqL[16*257];              // wq_raw[h][d], stride 257 (bank-safe)
    __shared__ float coefL[256*12];            // [d][c0..9, bias, pad]
    __shared__ float QL[128];
    __shared__ float bkL[128];
    wqF[4096 + t] = 0; wqF[4096 + 256 + t] = 0;
    if (t < 128){ QL[t] = Q[t]; bkL[t] = bk[t]; }
    __syncthreads();
    {
      const int d = t;
      float s1 = bn1_g[d] * rsqrtf(bn1_v[d] + EPS);
      #pragma unroll
      for (int c = 0; c < 10; ++c) coefL[d*12 + c] = conv_w[d*10 + c] * s1;
      coefL[d*12 + 10] = conv_b[d]*s1 + bn1_b[d] - bn1_m[d]*s1;
      coefL[d*12 + 11] = 0.f;
      #pragma unroll 4
      for (int h = 0; h < 16; ++h){
        float acc = 0.f;
        #pragma unroll
        for (int kk = 0; kk < 8; ++kk)
          acc += QL[h*8+kk] * Wk[(h*8+kk)*256 + d];   // coalesced across d=t
        wqL[h*257 + d] = acc;
      }
    }
    __syncthreads();
    if (t < 176){
      int h = t / 11, cc = t - h*11;               // cc 0..9 = conv chans, 10 = bias
      const float* wq = wqL + h*257;
      float acc = 0.f;
      #pragma unroll 4
      for (int d2 = 0; d2 < 256; ++d2)
        acc += coefL[d2*12 + cc] * wq[d2];
      acc *= INV_SQRT8;
      if (cc < 10){
        int lane = (cc < 8) ? h : (16 + h);
        int j = cc & 7;
        wqF[4096 + lane*8 + j] = f2bf(acc);
      } else {
        float qb = 0.f;
        #pragma unroll
        for (int kk = 0; kk < 8; ++kk) qb += QL[h*8+kk]*bkL[h*8+kk];
        biasq[h] = acc + qb * INV_SQRT8;
      }
    }
  } else if (bid == 72){                       // convwT [c][256] fp32 (bn1 folded)
    #pragma unroll
    for (int it = 0; it < 10; ++it){
      int e = it*256 + t;
      int c = e >> 8, d = e & 255;
      float s1 = bn1_g[d] * rsqrtf(bn1_v[d] + EPS);
      convwT[e] = conv_w[d*10 + c] * s1;
    }
  } else if (bid == 73){                       // small bias vectors
    {
      int d = t;
      float s1 = bn1_g[d] * rsqrtf(bn1_v[d] + EPS);
      convbE[d] = conv_b[d]*s1 + bn1_b[d] - bn1_m[d]*s1;
    }
    if (t < 128){
      float s2 = bn2_g[t] * rsqrtf(bn2_v[t] + EPS);
      b1E[t] = b1[t]*s2 + bn2_b[t] - bn2_m[t]*s2;
    }
    if (t < 32){
      float sd = bnd2_g[t] * rsqrtf(bnd2_v[t] + EPS);
      bd2E[t] = bd2[t]*sd + bnd2_b[t] - bnd2_m[t]*sd;
    }
  } else {                                     // bid 74: bd1E (oln_b folded)
    int n = t >> 2, si = t & 3;                // 4 threads per output n
    float acc = 0.f;
    #pragma unroll 8
    for (int i2 = 0; i2 < 32; ++i2){
      int i = si*32 + i2;
      acc += oln_b[i] * Wd1[n*128 + i];
    }
    redL[t] = acc;
    __syncthreads();
    if (t < 64){
      float sd = bnd1_g[t] * rsqrtf(bnd1_v[t] + EPS);
      float a = redL[4*t] + redL[4*t+1] + redL[4*t+2] + redL[4*t+3];
      bd1E[t] = bd1[t]*sd + bnd1_b[t] - bnd1_m[t]*sd + a*sd;
    }
  }
}

// ------------------------------------------------- K1: LN + PE + attention
// LDS: peR 25344 + attnF 3072 + featn 1536 + divL 512 + xL 2144 = 32608 B.
__global__ __launch_bounds__(256, 4) void k1_attn(
    const float* __restrict__ x, const float* __restrict__ ln1_g,
    const float* __restrict__ ln1_b,
    const unsigned short* __restrict__ wqF, const float* __restrict__ convwT,
    const float* __restrict__ convbE, const float* __restrict__ biasq,
    unsigned short* __restrict__ o_frag)
{
  __shared__ __align__(16) unsigned short peR[48*264];  // PE row-major [s-row][d]
  __shared__ __align__(16) float attnF[32*24];          // logits -> attn in place
  __shared__ __align__(16) unsigned short featn[48*16]; // LN'd feats, pad c>=10
  __shared__ __align__(16) float divL[128];             // div_i / (2*pi)
  __shared__ __align__(16) float xL[536];               // staged x; [528..535]=0
  float* gL = xL;  // alias: xL dead after P2; zeros at 528+ preserved

  const int t = threadIdx.x;
  const int b0 = blockIdx.x * 2;
  const int w = t >> 6, l = t & 63;

  // stage x (2 rows x 24 x 11 = 528 floats, coalesced) + zero pad
  if (t < 132)
    *(float4*)(xL + t*4) = *(const float4*)(x + (size_t)b0*264 + t*4);
  else if (t < 134)
    *(float4*)(xL + 528 + (t-132)*4) = make_float4(0.f,0.f,0.f,0.f);
  if (t < 128) divL[t] = exp2f((float)t * KDIV) * INV2PI;
  __syncthreads();                            // B1

  // P2: PE gen, 24 (mt,kc) combos balanced over 4 waves; polynomial sincos
  // (full-rate FMA/rndne only -- no quarter-rate trans ops).
  {
    const int g = (l >> 4) & 3, rlo = l & 15;
    #pragma unroll
    for (int it = 0; it < 6; ++it){
      int combo = it*4 + w;              // 0..23 = (mt,kc)
      int mt = combo >> 3, kc = combo & 7;
      int row = mt*16 + rlo;
      int run = kc*4 + g;                // covers d = run*8 .. run*8+7
      float p = xL[row*11];
      unsigned pk[4];
      #pragma unroll
      for (int q = 0; q < 4; ++q){
        float f  = p * divL[run*4 + q];            // revolutions
        float r  = f - __builtin_rintf(f);         // r in [-0.5, 0.5]
        float s  = r*r;
        float sp = fmaf(fmaf(fmaf(SA7, s, SA5), s, SA3), s, SA1) * r;
        float cp = fmaf(fmaf(fmaf(fmaf(CC8, s, CC6), s, CC4), s, CC2), s, CC0);
        pk[q] = pk2bf(sp, cp);
      }
      *(uint4*)(peR + row*264 + run*8) = make_uint4(pk[0], pk[1], pk[2], pk[3]);
    }
  }
  // LN on wave 3's lanes (concurrent with other waves' P2 tail)
  if (w == 3 && l < 48){
    const float* xr = xL + l*11;
    float f[10]; float mu = 0.f;
    #pragma unroll
    for (int c = 0; c < 10; ++c){ f[c] = xr[1+c]; mu += f[c]; }
    mu *= 0.1f;
    float var = 0.f;
    #pragma unroll
    for (int c = 0; c < 10; ++c){ float dv = f[c]-mu; var += dv*dv; }
    var *= 0.1f;
    float rs = rsqrtf(var + EPS);
    float fn[10];
    #pragma unroll
    for (int c = 0; c < 10; ++c) fn[c] = (f[c]-mu)*rs*ln1_g[c] + ln1_b[c];
    #pragma unroll
    for (int q = 0; q < 5; ++q)
      *(unsigned*)(featn + l*16 + 2*q) = pk2bf(fn[2*q], fn[2*q+1]);
    #pragma unroll
    for (int z = 0; z < 3; ++z)
      *(unsigned*)(featn + l*16 + 10 + 2*z) = 0u;
  }
  __syncthreads();                            // B2

  // P5: logits = [PE | featn] x [WqE | A] via MFMA, K = 288 (waves 0-2)
  const int m = l & 15, g = l >> 4;
  if (w < 3){
    const int mt = w;
    f32x4 acc = {0.f,0.f,0.f,0.f};
    #pragma unroll
    for (int kc = 0; kc < 8; ++kc){
      bf16x8 a = *(const bf16x8*)(peR + (mt*16 + m)*264 + kc*32 + g*8);
      bf16x8 b = *(const bf16x8*)(wqF + ((size_t)(kc*64 + l))*8);
      acc = __builtin_amdgcn_mfma_f32_16x16x32_bf16(a, b, acc, 0, 0, 0);
    }
    {
      const unsigned short* ap = (g < 2) ? (featn + (mt*16 + m)*16 + g*8)
                                         : (const unsigned short*)(xL + 528);
      bf16x8 a = *(const bf16x8*)ap;
      bf16x8 b = *(const bf16x8*)(wqF + ((size_t)(8*64 + l))*8);
      acc = __builtin_amdgcn_mfma_f32_16x16x32_bf16(a, b, acc, 0, 0, 0);
    }
    float bq = biasq[m];
    #pragma unroll
    for (int reg = 0; reg < 4; ++reg){
      int row = mt*16 + g*4 + reg;
      int bb = row >= 24; int s = row - bb*24;
      attnF[(bb*16+m)*24 + s] = acc[reg] + bq;
    }
  }
  __syncthreads();                            // B3

  // P6: softmax, 256 threads, 8-lane clusters per (bb,h), 3 s-values each
  {
    const int bh = t >> 3, ln = t & 7;
    float* L = attnF + bh*24;
    float v0 = L[ln], v1 = L[ln+8], v2 = L[ln+16];
    float mx = fmaxf(fmaxf(v0, v1), v2);
    mx = fmaxf(mx, __shfl_xor(mx, 1, 64));
    mx = fmaxf(mx, __shfl_xor(mx, 2, 64));
    mx = fmaxf(mx, __shfl_xor(mx, 4, 64));
    float p0 = exp2f((v0-mx)*LOG2E);
    float p1 = exp2f((v1-mx)*LOG2E);
    float p2 = exp2f((v2-mx)*LOG2E);
    float sm = p0 + p1 + p2;
    sm += __shfl_xor(sm, 1, 64);
    sm += __shfl_xor(sm, 2, 64);
    sm += __shfl_xor(sm, 4, 64);
    float inv = 1.f / sm;
    L[ln] = p0*inv; L[ln+8] = p1*inv; L[ln+16] = p2*inv;
  }
  __syncthreads();                            // B4

  // P6b on waves 2-3 (one MFMA per bb) overlapped with all-thread P7a below.
  if (w >= 2){
    const int bb = w - 2;
    const int q = g;                       // k-quad
    union { bf16x8 v; unsigned u[4]; } aF;
    if (q < 3){
      const float* ap = attnF + (bb*16 + m)*24 + q*8;
      float4 a0 = *(const float4*)ap;
      float4 a1 = *(const float4*)(ap + 4);
      aF.u[0] = pk2bf(a0.x, a0.y); aF.u[1] = pk2bf(a0.z, a0.w);
      aF.u[2] = pk2bf(a1.x, a1.y); aF.u[3] = pk2bf(a1.z, a1.w);
    } else {
      aF.u[0] = 0u; aF.u[1] = 0u; aF.u[2] = 0u; aF.u[3] = 0u;
    }
    union { bf16x8 v; unsigned short s[8]; } bF;
    #pragma unroll
    for (int j = 0; j < 8; ++j){
      int s = q*8 + j;
      bF.s[j] = (s < 24) ? featn[(bb*24 + s)*16 + m] : (unsigned short)0;
    }
    f32x4 z = {0.f,0.f,0.f,0.f};
    f32x4 ga = __builtin_amdgcn_mfma_f32_16x16x32_bf16(aF.v, bF.v, z, 0,0,0);
    if (m < 12){
      #pragma unroll
      for (int reg = 0; reg < 4; ++reg){
        int h = q*4 + reg;
        gL[(bb*16+h)*12 + m] = ga[reg];
      }
    }
  }

  // P7a: pe-part accumulation (all threads; needs only attnF + peR)
  const int bb7 = t >> 7, dp = t & 127;
  const int d0 = dp*2, h7 = dp >> 3;
  float2 o2; o2.x = 0.f; o2.y = 0.f;
  {
    float A[24];
    const float* Ab = attnF + (bb7*16+h7)*24;
    #pragma unroll
    for (int q4 = 0; q4 < 6; ++q4)
      *(float4*)(A + q4*4) = *(const float4*)(Ab + q4*4);
    const unsigned short* pr = peR + bb7*24*264 + d0;
    #pragma unroll
    for (int s = 0; s < 24; ++s){
      unsigned u = *(const unsigned*)(pr + s*264);
      o2.x += A[s] * asf(u << 16);
      o2.y += A[s] * asf(u & 0xFFFF0000u);
    }
  }
  __syncthreads();                            // B5 (gL ready)

  // P7b: conv-fold add + store in MFMA-A-frag layout for k2.
  {
    float2 cb2 = *(const float2*)(convbE + d0);
    o2.x += cb2.x; o2.y += cb2.y;
    const float* gp = gL + (bb7*16+h7)*12;
    #pragma unroll
    for (int c = 0; c < 10; ++c){
      float2 cw = *(const float2*)(convwT + c*256 + d0);
      o2.x += cw.x * gp[c];
      o2.y += cw.y * gp[c];
    }
    const int row = b0 + bb7;
    const int rt = row >> 4, mm = row & 15;
    const int kc = d0 >> 5, gg = (d0 >> 3) & 3, j = d0 & 7;
    *(unsigned*)(o_frag + ((size_t)((rt*8+kc)*64 + gg*16 + mm))*8 + j)
        = pk2bf(o2.x, o2.y);
  }
}

// ---------------------------------------------------------- K2: MLP head
// 16 rows/block x 1024 blocks; A-loads contiguous b128 from frag-layout o.
__global__ __launch_bounds__(256, 4) void k2_mlp(
    const unsigned short* __restrict__ o_frag,
    const unsigned short* __restrict__ w1F, const float* __restrict__ b1E,
    const unsigned short* __restrict__ wd1F, const float* __restrict__ bd1E,
    const unsigned short* __restrict__ wd2F, const float* __restrict__ bd2E,
    const unsigned short* __restrict__ wd3F, const float* __restrict__ bd3,
    float* __restrict__ out)
{
  __shared__ float mL[16*132];
  __shared__ unsigned short mh[16*136];
  __shared__ unsigned short d1L[16*72];
  __shared__ unsigned short d2L[16*40];
  __shared__ float redL[64];
  __shared__ float stats[32];

  const int t = threadIdx.x;
  const int w = t >> 6, l = t & 63;
  const size_t rowBase = (size_t)blockIdx.x * 16;
  const int rt = blockIdx.x;                  // 16-row tile index
  const int g8  = (l >> 4) << 3;
  const int c15 = l & 15;

  // S1: m_pre = o @ W1_eff^T (+relu, bn2 folded); wave w covers nt=2w,2w+1
  {
    f32x4 acc[2];
    { f32x4 z = {0.f,0.f,0.f,0.f}; acc[0] = z; acc[1] = z; }
    #pragma unroll
    for (int kc = 0; kc < 8; ++kc){
      bf16x8 a = *(const bf16x8*)(o_frag + ((size_t)((rt*8+kc)*64 + l))*8);
      #pragma unroll
      for (int n2 = 0; n2 < 2; ++n2){
        int nt = 2*w + n2;
        bf16x8 b = *(const bf16x8*)(w1F + ((size_t)((nt*8+kc)*64 + l))*8);
        acc[n2] = __builtin_amdgcn_mfma_f32_16x16x32_bf16(a, b, acc[n2], 0,0,0);
      }
    }
    #pragma unroll
    for (int n2 = 0; n2 < 2; ++n2){
      int col = (2*w + n2)*16 + c15;
      float be = b1E[col];
      #pragma unroll
      for (int reg = 0; reg < 4; ++reg){
        int row = ((l>>4)<<2) + reg;
        mL[row*132 + col] = fmaxf(acc[n2][reg] + be, 0.f);
      }
    }
  }
  __syncthreads();

  // S3: LN stats over 128
  if (t < 32){
    const float* R = mL + (t>>1)*132 + (t&1)*64;
    float s = 0.f, q = 0.f;
    for (int k = 0; k < 64; ++k){ float v = R[k]; s += v; q += v*v; }
    redL[t*2] = s; redL[t*2+1] = q;
  }
  __syncthreads();
  if (t < 16){
    float s = redL[4*t] + redL[4*t+2];
    float q = redL[4*t+1] + redL[4*t+3];
    float mu = s * (1.f/128.f);
    float var = q * (1.f/128.f) - mu*mu;
    stats[2*t] = mu; stats[2*t+1] = rsqrtf(var + EPS);
  }
  __syncthreads();

  // S4: mhat in bf16 (oln g/b folded into Wd1F/bd1E); 16 rows x 16 runs
  {
    int r = t >> 4, run = t & 15;
    float mu = stats[2*r], rs = stats[2*r+1];
    const float* R = mL + r*132 + run*8;
    unsigned pk[4];
    #pragma unroll
    for (int q = 0; q < 4; ++q)
      pk[q] = pk2bf((R[2*q]-mu)*rs, (R[2*q+1]-mu)*rs);
    *(uint4*)(mh + r*136 + run*8) = make_uint4(pk[0], pk[1], pk[2], pk[3]);
  }
  __syncthreads();

  // S5: d1 = relu(mhat @ Wd1_eff^T + bd1E); wave w -> nt=w
  {
    const int nt = w;
    f32x4 acc = {0.f,0.f,0.f,0.f};
    #pragma unroll
    for (int kc = 0; kc < 4; ++kc){
      bf16x8 b = *(const bf16x8*)(wd1F + ((size_t)((nt*4+kc)*64 + l))*8);
      bf16x8 a = *(const bf16x8*)(mh + c15*136 + kc*32 + g8);
      acc = __builtin_amdgcn_mfma_f32_16x16x32_bf16(a, b, acc, 0,0,0);
    }
    int col = nt*16 + c15;
    float be = bd1E[col];
    #pragma unroll
    for (int reg = 0; reg < 4; ++reg){
      int row = ((l>>4)<<2) + reg;
      d1L[row*72 + col] = f2bf(fmaxf(acc[reg] + be, 0.f));
    }
  }
  __syncthreads();

  // S6: d2 = relu(d1 @ Wd2_eff^T + bd2E); waves 0,1 -> nt=w
  if (w < 2){
    const int nt = w;
    f32x4 acc = {0.f,0.f,0.f,0.f};
    #pragma unroll
    for (int kc = 0; kc < 2; ++kc){
      bf16x8 a = *(const bf16x8*)(d1L + c15*72 + kc*32 + g8);
      bf16x8 b = *(const bf16x8*)(wd2F + ((size_t)((nt*2+kc)*64 + l))*8);
      acc = __builtin_amdgcn_mfma_f32_16x16x32_bf16(a, b, acc, 0,0,0);
    }
    int col = nt*16 + c15;
    float be = bd2E[col];
    #pragma unroll
    for (int reg = 0; reg < 4; ++reg){
      int row = ((l>>4)<<2) + reg;
      d2L[row*40 + col] = f2bf(fmaxf(acc[reg] + be, 0.f));
    }
  }
  __syncthreads();

  // S7: out = d2 @ Wd3^T + bd3; waves 0,1 -> nt=w
  if (w < 2){
    const int nt = w;
    bf16x8 a = *(const bf16x8*)(d2L + c15*40 + g8);
    bf16x8 b = *(const bf16x8*)(wd3F + ((size_t)(nt*64 + l))*8);
    f32x4 acc = {0.f,0.f,0.f,0.f};
    acc = __builtin_amdgcn_mfma_f32_16x16x32_bf16(a, b, acc, 0,0,0);
    int col = nt*16 + c15;
    if (col < 20){
      float be = bd3[col];
      #pragma unroll
      for (int reg = 0; reg < 4; ++reg){
        int row = ((l>>4)<<2) + reg;
        out[(rowBase + row)*20 + col] = acc[reg] + be;
      }
    }
  }
}

// ---------------------------------------------------------------- launcher
extern "C" void kernel_launch(void* const* d_in, const int* in_sizes, int n_in,
                              void* d_out, int out_size, void* d_ws, size_t ws_size,
                              hipStream_t stream)
{
  (void)in_sizes; (void)n_in; (void)out_size; (void)ws_size;
  const float* x      = (const float*)d_in[0];
  const float* ln1_g  = (const float*)d_in[1];
  const float* ln1_b  = (const float*)d_in[2];
  const float* conv_w = (const float*)d_in[3];
  const float* conv_b = (const float*)d_in[4];
  const float* bn1_g  = (const float*)d_in[5];
  const float* bn1_b  = (const float*)d_in[6];
  const float* bn1_m  = (const float*)d_in[7];
  const float* bn1_v  = (const float*)d_in[8];
  const float* Q      = (const float*)d_in[9];
  const float* Wk     = (const float*)d_in[10];
  const float* bk     = (const float*)d_in[11];
  const float* W1     = (const float*)d_in[12];
  const float* b1     = (const float*)d_in[13];
  const float* bn2_g  = (const float*)d_in[14];
  const float* bn2_b  = (const float*)d_in[15];
  const float* bn2_m  = (const float*)d_in[16];
  const float* bn2_v  = (const float*)d_in[17];
  const float* oln_g  = (const float*)d_in[18];
  const float* oln_b  = (const float*)d_in[19];
  const float* Wd1    = (const float*)d_in[20];
  const float* bd1    = (const float*)d_in[21];
  const float* bnd1_g = (const float*)d_in[22];
  const float* bnd1_b = (const float*)d_in[23];
  const float* bnd1_m = (const float*)d_in[24];
  const float* bnd1_v = (const float*)d_in[25];
  const float* Wd2    = (const float*)d_in[26];
  const float* bd2    = (const float*)d_in[27];
  const float* bnd2_g = (const float*)d_in[28];
  const float* bnd2_b = (const float*)d_in[29];
  const float* bnd2_m = (const float*)d_in[30];
  const float* bnd2_v = (const float*)d_in[31];
  const float* Wd3    = (const float*)d_in[32];
  const float* bd3    = (const float*)d_in[33];

  char* ws = (char*)d_ws;
  unsigned short* wqF  = (unsigned short*)(ws + 0);        // 9216 B
  unsigned short* w1F  = (unsigned short*)(ws + 9216);     // 65536 B
  unsigned short* wd1F = (unsigned short*)(ws + 74752);    // 16384 B
  unsigned short* wd2F = (unsigned short*)(ws + 91136);    // 4096 B
  unsigned short* wd3F = (unsigned short*)(ws + 95232);    // 2048 B
  float* convwT = (float*)(ws + 97280);                    // 10240 B
  float* convbE = (float*)(ws + 107520);                   // 1024 B
  float* biasq  = (float*)(ws + 108544);                   // 64 B
  float* b1E    = (float*)(ws + 108608);                   // 512 B
  float* bd1E   = (float*)(ws + 109120);                   // 256 B
  float* bd2E   = (float*)(ws + 109376);                   // 128 B
  unsigned short* o_frag = (unsigned short*)(ws + 109568); // 8 MB

  hipLaunchKernelGGL(k0_pre, dim3(78), dim3(256), 0, stream,
      conv_w, conv_b, bn1_g, bn1_b, bn1_m, bn1_v, Q, Wk, bk,
      W1, b1, bn2_g, bn2_b, bn2_m, bn2_v, oln_g, oln_b,
      Wd1, bd1, bnd1_g, bnd1_b, bnd1_m, bnd1_v,
      Wd2, bd2, bnd2_g, bnd2_b, bnd2_m, bnd2_v, Wd3,
      wqF, w1F, wd1F, wd2F, wd3F, convwT, convbE, biasq, b1E, bd1E, bd2E);

  hipLaunchKernelGGL(k1_attn, dim3(8192), dim3(256), 0, stream,
      x, ln1_g, ln1_b, wqF, convwT, convbE, biasq, o_frag);

  hipLaunchKernelGGL(k2_mlp, dim3(1024), dim3(256), 0, stream,
      o_frag, w1F, b1E, wd1F, bd1E, wd2F, bd2E, wd3F, bd3, (float*)d_out);
}

// Round 8
// 179.736 us; speedup vs baseline: 1.0361x; 1.0361x over previous
//
#include <hip/hip_runtime.h>
#include <hip/hip_bf16.h>

// LTAE fused implementation for gfx950.
// K1 (R8): trans sincos (proven R5); bf16x2 packing via 3-instr software
//     round-half-up + v_perm_b32 merge (R7's v_cvt_pk_bf16_f32 has non-RNE
//     rounding on gfx950 -> failed; builtin expands to ~6-instr RNE).
//     P6b on waves 2-3 overlapped with all-thread P7a.

typedef __attribute__((ext_vector_type(8))) short bf16x8;   // 8 bf16 (4 VGPRs)
typedef __attribute__((ext_vector_type(4))) float f32x4;

#define EPS 1e-5f
#define INV_SQRT8 0.35355339059327373f
#define KDIV (-0.07785768972392256f)   /* -log2(1000)/128 */
#define INV2PI 0.15915494309189535f
#define LOG2E 1.4426950408889634f

__device__ __forceinline__ unsigned short f2bf(float f){
  union { float f; unsigned u; } v; v.f = f;
  unsigned r = v.u + 0x7FFFu + ((v.u >> 16) & 1u);   // RNE
  return (unsigned short)(r >> 16);
}
__device__ __forceinline__ float bf2f(unsigned short h){
  union { unsigned u; float f; } v; v.u = ((unsigned)h) << 16; return v.f;
}
__device__ __forceinline__ float asf(unsigned u){
  union { unsigned u; float f; } v; v.u = u; return v.f;
}
// packed f32x2 -> bf16x2, round-half-up (2x v_add_u32 + v_perm_b32).
// D.lo16 = bf16(lo), D.hi16 = bf16(hi). Differs from RNE only on exact ties.
__device__ __forceinline__ unsigned pk2bf(float lo, float hi){
  union { float f; unsigned u; } a, b;
  a.f = lo; b.f = hi;
  return __builtin_amdgcn_perm(b.u + 0x8000u, a.u + 0x8000u, 0x07060302u);
}

// ---------------------------------------------------------------- K0: prepack
__global__ __launch_bounds__(256) void k0_pre(
    const float* __restrict__ conv_w, const float* __restrict__ conv_b,
    const float* __restrict__ bn1_g, const float* __restrict__ bn1_b,
    const float* __restrict__ bn1_m, const float* __restrict__ bn1_v,
    const float* __restrict__ Q, const float* __restrict__ Wk,
    const float* __restrict__ bk,
    const float* __restrict__ W1, const float* __restrict__ b1,
    const float* __restrict__ bn2_g, const float* __restrict__ bn2_b,
    const float* __restrict__ bn2_m, const float* __restrict__ bn2_v,
    const float* __restrict__ oln_g, const float* __restrict__ oln_b,
    const float* __restrict__ Wd1, const float* __restrict__ bd1,
    const float* __restrict__ bnd1_g, const float* __restrict__ bnd1_b,
    const float* __restrict__ bnd1_m, const float* __restrict__ bnd1_v,
    const float* __restrict__ Wd2, const float* __restrict__ bd2,
    const float* __restrict__ bnd2_g, const float* __restrict__ bnd2_b,
    const float* __restrict__ bnd2_m, const float* __restrict__ bnd2_v,
    const float* __restrict__ Wd3,
    unsigned short* __restrict__ wqF, unsigned short* __restrict__ w1F,
    unsigned short* __restrict__ wd1F, unsigned short* __restrict__ wd2F,
    unsigned short* __restrict__ wd3F,
    float* __restrict__ convwT, float* __restrict__ convbE,
    float* __restrict__ biasq, float* __restrict__ b1E,
    float* __restrict__ bd1E, float* __restrict__ bd2E)
{
  __shared__ float redL[256];
  const int t = threadIdx.x;
  const int bid = blockIdx.x;

  if (bid < 64){                               // W1F: [8nt][8kc][64][8]
    for (int e = bid*512 + t; e < bid*512 + 512; e += 256){
      int j = e & 7, lj = (e >> 3) & 63, kc = (e >> 9) & 7, nt = (e >> 12) & 7;
      int n = nt*16 + (lj & 15);
      int k = kc*32 + ((lj >> 4) << 3) + j;
      float s2 = bn2_g[n] * rsqrtf(bn2_v[n] + EPS);
      w1F[e] = f2bf(W1[n*256 + k] * s2);
    }
  } else if (bid < 68){                        // Wd1F: [4nt][4kc][64][8], oln_g folded
    int base = (bid - 64)*2048;
    #pragma unroll 4
    for (int it = 0; it < 8; ++it){
      int e = base + it*256 + t;
      int j = e & 7, lj = (e >> 3) & 63, kc = (e >> 9) & 3, nt = (e >> 11) & 3;
      int n = nt*16 + (lj & 15);
      int k = kc*32 + ((lj >> 4) << 3) + j;
      float sd = bnd1_g[n] * rsqrtf(bnd1_v[n] + EPS);
      wd1F[e] = f2bf(Wd1[n*128 + k] * sd * oln_g[k]);
    }
  } else if (bid == 68){                       // Wd2F: [2nt][2kc][64][8]
    #pragma unroll 4
    for (int it = 0; it < 8; ++it){
      int e = it*256 + t;
      int j = e & 7, lj = (e >> 3) & 63, kc = (e >> 9) & 1, nt = (e >> 10) & 1;
      int n = nt*16 + (lj & 15);
      int k = kc*32 + ((lj >> 4) << 3) + j;
      float sd = bnd2_g[n] * rsqrtf(bnd2_v[n] + EPS);
      wd2F[e] = f2bf(Wd2[n*64 + k] * sd);
    }
  } else if (bid == 69){                       // Wd3F: [2nt][64][8], zero pad n>=20
    #pragma unroll
    for (int it = 0; it < 4; ++it){
      int e = it*256 + t;
      int j = e & 7, lj = (e >> 3) & 63, nt = (e >> 9) & 1;
      int n = nt*16 + (lj & 15);
      int k = ((lj >> 4) << 3) + j;
      float v = (n < 20) ? Wd3[n*32 + k] : 0.f;
      wd3F[e] = f2bf(v);
    }
  } else if (bid == 70 || bid >= 75){          // WqF kc 0..7 (split over 4 blocks)
    int c0 = (bid == 70) ? 0 : (bid - 74)*4;   // it base: 0,4,8,12
    #pragma unroll
    for (int i2 = 0; i2 < 4; ++i2){
      int e = (c0 + i2)*256 + t;
      int j = e & 7, lj = (e >> 3) & 63, kc = (e >> 9) & 7;
      int h = lj & 15;
      int dd = kc*32 + ((lj >> 4) << 3) + j;
      float acc = 0.f;
      #pragma unroll
      for (int kk = 0; kk < 8; ++kk)
        acc += Q[h*8+kk] * Wk[(h*8+kk)*256 + dd];
      wqF[e] = f2bf(acc * INV_SQRT8);
    }
  } else if (bid == 71){                       // WqF kc=8 (conv fold A[h,c]) + biasq
    __shared__ float wqL[16*257];              // wq_raw[h][d], stride 257 (bank-safe)
    __shared__ float coefL[256*12];            // [d][c0..9, bias, pad]
    __shared__ float QL[128];
    __shared__ float bkL[128];
    wqF[4096 + t] = 0; wqF[4096 + 256 + t] = 0;
    if (t < 128){ QL[t] = Q[t]; bkL[t] = bk[t]; }
    __syncthreads();
    {
      const int d = t;
      float s1 = bn1_g[d] * rsqrtf(bn1_v[d] + EPS);
      #pragma unroll
      for (int c = 0; c < 10; ++c) coefL[d*12 + c] = conv_w[d*10 + c] * s1;
      coefL[d*12 + 10] = conv_b[d]*s1 + bn1_b[d] - bn1_m[d]*s1;
      coefL[d*12 + 11] = 0.f;
      #pragma unroll 4
      for (int h = 0; h < 16; ++h){
        float acc = 0.f;
        #pragma unroll
        for (int kk = 0; kk < 8; ++kk)
          acc += QL[h*8+kk] * Wk[(h*8+kk)*256 + d];   // coalesced across d=t
        wqL[h*257 + d] = acc;
      }
    }
    __syncthreads();
    if (t < 176){
      int h = t / 11, cc = t - h*11;               // cc 0..9 = conv chans, 10 = bias
      const float* wq = wqL + h*257;
      float acc = 0.f;
      #pragma unroll 4
      for (int d2 = 0; d2 < 256; ++d2)
        acc += coefL[d2*12 + cc] * wq[d2];
      acc *= INV_SQRT8;
      if (cc < 10){
        int lane = (cc < 8) ? h : (16 + h);
        int j = cc & 7;
        wqF[4096 + lane*8 + j] = f2bf(acc);
      } else {
        float qb = 0.f;
        #pragma unroll
        for (int kk = 0; kk < 8; ++kk) qb += QL[h*8+kk]*bkL[h*8+kk];
        biasq[h] = acc + qb * INV_SQRT8;
      }
    }
  } else if (bid == 72){                       // convwT [c][256] fp32 (bn1 folded)
    #pragma unroll
    for (int it = 0; it < 10; ++it){
      int e = it*256 + t;
      int c = e >> 8, d = e & 255;
      float s1 = bn1_g[d] * rsqrtf(bn1_v[d] + EPS);
      convwT[e] = conv_w[d*10 + c] * s1;
    }
  } else if (bid == 73){                       // small bias vectors
    {
      int d = t;
      float s1 = bn1_g[d] * rsqrtf(bn1_v[d] + EPS);
      convbE[d] = conv_b[d]*s1 + bn1_b[d] - bn1_m[d]*s1;
    }
    if (t < 128){
      float s2 = bn2_g[t] * rsqrtf(bn2_v[t] + EPS);
      b1E[t] = b1[t]*s2 + bn2_b[t] - bn2_m[t]*s2;
    }
    if (t < 32){
      float sd = bnd2_g[t] * rsqrtf(bnd2_v[t] + EPS);
      bd2E[t] = bd2[t]*sd + bnd2_b[t] - bnd2_m[t]*sd;
    }
  } else {                                     // bid 74: bd1E (oln_b folded)
    int n = t >> 2, si = t & 3;                // 4 threads per output n
    float acc = 0.f;
    #pragma unroll 8
    for (int i2 = 0; i2 < 32; ++i2){
      int i = si*32 + i2;
      acc += oln_b[i] * Wd1[n*128 + i];
    }
    redL[t] = acc;
    __syncthreads();
    if (t < 64){
      float sd = bnd1_g[t] * rsqrtf(bnd1_v[t] + EPS);
      float a = redL[4*t] + redL[4*t+1] + redL[4*t+2] + redL[4*t+3];
      bd1E[t] = bd1[t]*sd + bnd1_b[t] - bnd1_m[t]*sd + a*sd;
    }
  }
}

// ------------------------------------------------- K1: LN + PE + attention
// LDS: peR 25344 + attnF 3072 + featn 1536 + divL 512 + xL 2144 = 32608 B.
__global__ __launch_bounds__(256, 4) void k1_attn(
    const float* __restrict__ x, const float* __restrict__ ln1_g,
    const float* __restrict__ ln1_b,
    const unsigned short* __restrict__ wqF, const float* __restrict__ convwT,
    const float* __restrict__ convbE, const float* __restrict__ biasq,
    unsigned short* __restrict__ o_frag)
{
  __shared__ __align__(16) unsigned short peR[48*264];  // PE row-major [s-row][d]
  __shared__ __align__(16) float attnF[32*24];          // logits -> attn in place
  __shared__ __align__(16) unsigned short featn[48*16]; // LN'd feats, pad c>=10
  __shared__ __align__(16) float divL[128];             // div_i / (2*pi)
  __shared__ __align__(16) float xL[536];               // staged x; [528..535]=0
  float* gL = xL;  // alias: xL dead after P2; zeros at 528+ preserved

  const int t = threadIdx.x;
  const int b0 = blockIdx.x * 2;
  const int w = t >> 6, l = t & 63;

  // stage x (2 rows x 24 x 11 = 528 floats, coalesced) + zero pad
  if (t < 132)
    *(float4*)(xL + t*4) = *(const float4*)(x + (size_t)b0*264 + t*4);
  else if (t < 134)
    *(float4*)(xL + 528 + (t-132)*4) = make_float4(0.f,0.f,0.f,0.f);
  if (t < 128) divL[t] = exp2f((float)t * KDIV) * INV2PI;
  __syncthreads();                            // B1

  // P2: PE gen, 24 (mt,kc) combos balanced over 4 waves; HW trans sincos.
  {
    const int g = (l >> 4) & 3, rlo = l & 15;
    #pragma unroll
    for (int it = 0; it < 6; ++it){
      int combo = it*4 + w;              // 0..23 = (mt,kc)
      int mt = combo >> 3, kc = combo & 7;
      int row = mt*16 + rlo;
      int run = kc*4 + g;                // covers d = run*8 .. run*8+7
      float p = xL[row*11];
      unsigned pk[4];
      #pragma unroll
      for (int q = 0; q < 4; ++q){
        float fr = __builtin_amdgcn_fractf(p * divL[run*4 + q]);
        pk[q] = pk2bf(__builtin_amdgcn_sinf(fr), __builtin_amdgcn_cosf(fr));
      }
      *(uint4*)(peR + row*264 + run*8) = make_uint4(pk[0], pk[1], pk[2], pk[3]);
    }
  }
  // LN on wave 3's lanes (concurrent with other waves' P2 tail)
  if (w == 3 && l < 48){
    const float* xr = xL + l*11;
    float f[10]; float mu = 0.f;
    #pragma unroll
    for (int c = 0; c < 10; ++c){ f[c] = xr[1+c]; mu += f[c]; }
    mu *= 0.1f;
    float var = 0.f;
    #pragma unroll
    for (int c = 0; c < 10; ++c){ float dv = f[c]-mu; var += dv*dv; }
    var *= 0.1f;
    float rs = rsqrtf(var + EPS);
    float fn[10];
    #pragma unroll
    for (int c = 0; c < 10; ++c) fn[c] = (f[c]-mu)*rs*ln1_g[c] + ln1_b[c];
    #pragma unroll
    for (int q = 0; q < 5; ++q)
      *(unsigned*)(featn + l*16 + 2*q) = pk2bf(fn[2*q], fn[2*q+1]);
    #pragma unroll
    for (int z = 0; z < 3; ++z)
      *(unsigned*)(featn + l*16 + 10 + 2*z) = 0u;
  }
  __syncthreads();                            // B2

  // P5: logits = [PE | featn] x [WqE | A] via MFMA, K = 288 (waves 0-2)
  const int m = l & 15, g = l >> 4;
  if (w < 3){
    const int mt = w;
    f32x4 acc = {0.f,0.f,0.f,0.f};
    #pragma unroll
    for (int kc = 0; kc < 8; ++kc){
      bf16x8 a = *(const bf16x8*)(peR + (mt*16 + m)*264 + kc*32 + g*8);
      bf16x8 b = *(const bf16x8*)(wqF + ((size_t)(kc*64 + l))*8);
      acc = __builtin_amdgcn_mfma_f32_16x16x32_bf16(a, b, acc, 0, 0, 0);
    }
    {
      const unsigned short* ap = (g < 2) ? (featn + (mt*16 + m)*16 + g*8)
                                         : (const unsigned short*)(xL + 528);
      bf16x8 a = *(const bf16x8*)ap;
      bf16x8 b = *(const bf16x8*)(wqF + ((size_t)(8*64 + l))*8);
      acc = __builtin_amdgcn_mfma_f32_16x16x32_bf16(a, b, acc, 0, 0, 0);
    }
    float bq = biasq[m];
    #pragma unroll
    for (int reg = 0; reg < 4; ++reg){
      int row = mt*16 + g*4 + reg;
      int bb = row >= 24; int s = row - bb*24;
      attnF[(bb*16+m)*24 + s] = acc[reg] + bq;
    }
  }
  __syncthreads();                            // B3

  // P6: softmax, 256 threads, 8-lane clusters per (bb,h), 3 s-values each
  {
    const int bh = t >> 3, ln = t & 7;
    float* L = attnF + bh*24;
    float v0 = L[ln], v1 = L[ln+8], v2 = L[ln+16];
    float mx = fmaxf(fmaxf(v0, v1), v2);
    mx = fmaxf(mx, __shfl_xor(mx, 1, 64));
    mx = fmaxf(mx, __shfl_xor(mx, 2, 64));
    mx = fmaxf(mx, __shfl_xor(mx, 4, 64));
    float p0 = exp2f((v0-mx)*LOG2E);
    float p1 = exp2f((v1-mx)*LOG2E);
    float p2 = exp2f((v2-mx)*LOG2E);
    float sm = p0 + p1 + p2;
    sm += __shfl_xor(sm, 1, 64);
    sm += __shfl_xor(sm, 2, 64);
    sm += __shfl_xor(sm, 4, 64);
    float inv = 1.f / sm;
    L[ln] = p0*inv; L[ln+8] = p1*inv; L[ln+16] = p2*inv;
  }
  __syncthreads();                            // B4

  // P6b on waves 2-3 (one MFMA per bb) overlapped with all-thread P7a below.
  if (w >= 2){
    const int bb = w - 2;
    const int q = g;                       // k-quad
    union { bf16x8 v; unsigned u[4]; } aF;
    if (q < 3){
      const float* ap = attnF + (bb*16 + m)*24 + q*8;
      float4 a0 = *(const float4*)ap;
      float4 a1 = *(const float4*)(ap + 4);
      aF.u[0] = pk2bf(a0.x, a0.y); aF.u[1] = pk2bf(a0.z, a0.w);
      aF.u[2] = pk2bf(a1.x, a1.y); aF.u[3] = pk2bf(a1.z, a1.w);
    } else {
      aF.u[0] = 0u; aF.u[1] = 0u; aF.u[2] = 0u; aF.u[3] = 0u;
    }
    union { bf16x8 v; unsigned short s[8]; } bF;
    #pragma unroll
    for (int j = 0; j < 8; ++j){
      int s = q*8 + j;
      bF.s[j] = (s < 24) ? featn[(bb*24 + s)*16 + m] : (unsigned short)0;
    }
    f32x4 z = {0.f,0.f,0.f,0.f};
    f32x4 ga = __builtin_amdgcn_mfma_f32_16x16x32_bf16(aF.v, bF.v, z, 0,0,0);
    if (m < 12){
      #pragma unroll
      for (int reg = 0; reg < 4; ++reg){
        int h = q*4 + reg;
        gL[(bb*16+h)*12 + m] = ga[reg];
      }
    }
  }

  // P7a: pe-part accumulation (all threads; needs only attnF + peR)
  const int bb7 = t >> 7, dp = t & 127;
  const int d0 = dp*2, h7 = dp >> 3;
  float2 o2; o2.x = 0.f; o2.y = 0.f;
  {
    float A[24];
    const float* Ab = attnF + (bb7*16+h7)*24;
    #pragma unroll
    for (int q4 = 0; q4 < 6; ++q4)
      *(float4*)(A + q4*4) = *(const float4*)(Ab + q4*4);
    const unsigned short* pr = peR + bb7*24*264 + d0;
    #pragma unroll
    for (int s = 0; s < 24; ++s){
      unsigned u = *(const unsigned*)(pr + s*264);
      o2.x += A[s] * asf(u << 16);
      o2.y += A[s] * asf(u & 0xFFFF0000u);
    }
  }
  __syncthreads();                            // B5 (gL ready)

  // P7b: conv-fold add + store in MFMA-A-frag layout for k2.
  {
    float2 cb2 = *(const float2*)(convbE + d0);
    o2.x += cb2.x; o2.y += cb2.y;
    const float* gp = gL + (bb7*16+h7)*12;
    #pragma unroll
    for (int c = 0; c < 10; ++c){
      float2 cw = *(const float2*)(convwT + c*256 + d0);
      o2.x += cw.x * gp[c];
      o2.y += cw.y * gp[c];
    }
    const int row = b0 + bb7;
    const int rt = row >> 4, mm = row & 15;
    const int kc = d0 >> 5, gg = (d0 >> 3) & 3, j = d0 & 7;
    *(unsigned*)(o_frag + ((size_t)((rt*8+kc)*64 + gg*16 + mm))*8 + j)
        = pk2bf(o2.x, o2.y);
  }
}

// ---------------------------------------------------------- K2: MLP head
// 16 rows/block x 1024 blocks; A-loads contiguous b128 from frag-layout o.
__global__ __launch_bounds__(256, 4) void k2_mlp(
    const unsigned short* __restrict__ o_frag,
    const unsigned short* __restrict__ w1F, const float* __restrict__ b1E,
    const unsigned short* __restrict__ wd1F, const float* __restrict__ bd1E,
    const unsigned short* __restrict__ wd2F, const float* __restrict__ bd2E,
    const unsigned short* __restrict__ wd3F, const float* __restrict__ bd3,
    float* __restrict__ out)
{
  __shared__ float mL[16*132];
  __shared__ unsigned short mh[16*136];
  __shared__ unsigned short d1L[16*72];
  __shared__ unsigned short d2L[16*40];
  __shared__ float redL[64];
  __shared__ float stats[32];

  const int t = threadIdx.x;
  const int w = t >> 6, l = t & 63;
  const size_t rowBase = (size_t)blockIdx.x * 16;
  const int rt = blockIdx.x;                  // 16-row tile index
  const int g8  = (l >> 4) << 3;
  const int c15 = l & 15;

  // S1: m_pre = o @ W1_eff^T (+relu, bn2 folded); wave w covers nt=2w,2w+1
  {
    f32x4 acc[2];
    { f32x4 z = {0.f,0.f,0.f,0.f}; acc[0] = z; acc[1] = z; }
    #pragma unroll
    for (int kc = 0; kc < 8; ++kc){
      bf16x8 a = *(const bf16x8*)(o_frag + ((size_t)((rt*8+kc)*64 + l))*8);
      #pragma unroll
      for (int n2 = 0; n2 < 2; ++n2){
        int nt = 2*w + n2;
        bf16x8 b = *(const bf16x8*)(w1F + ((size_t)((nt*8+kc)*64 + l))*8);
        acc[n2] = __builtin_amdgcn_mfma_f32_16x16x32_bf16(a, b, acc[n2], 0,0,0);
      }
    }
    #pragma unroll
    for (int n2 = 0; n2 < 2; ++n2){
      int col = (2*w + n2)*16 + c15;
      float be = b1E[col];
      #pragma unroll
      for (int reg = 0; reg < 4; ++reg){
        int row = ((l>>4)<<2) + reg;
        mL[row*132 + col] = fmaxf(acc[n2][reg] + be, 0.f);
      }
    }
  }
  __syncthreads();

  // S3: LN stats over 128
  if (t < 32){
    const float* R = mL + (t>>1)*132 + (t&1)*64;
    float s = 0.f, q = 0.f;
    for (int k = 0; k < 64; ++k){ float v = R[k]; s += v; q += v*v; }
    redL[t*2] = s; redL[t*2+1] = q;
  }
  __syncthreads();
  if (t < 16){
    float s = redL[4*t] + redL[4*t+2];
    float q = redL[4*t+1] + redL[4*t+3];
    float mu = s * (1.f/128.f);
    float var = q * (1.f/128.f) - mu*mu;
    stats[2*t] = mu; stats[2*t+1] = rsqrtf(var + EPS);
  }
  __syncthreads();

  // S4: mhat in bf16 (oln g/b folded into Wd1F/bd1E); 16 rows x 16 runs
  {
    int r = t >> 4, run = t & 15;
    float mu = stats[2*r], rs = stats[2*r+1];
    const float* R = mL + r*132 + run*8;
    unsigned pk[4];
    #pragma unroll
    for (int q = 0; q < 4; ++q)
      pk[q] = pk2bf((R[2*q]-mu)*rs, (R[2*q+1]-mu)*rs);
    *(uint4*)(mh + r*136 + run*8) = make_uint4(pk[0], pk[1], pk[2], pk[3]);
  }
  __syncthreads();

  // S5: d1 = relu(mhat @ Wd1_eff^T + bd1E); wave w -> nt=w
  {
    const int nt = w;
    f32x4 acc = {0.f,0.f,0.f,0.f};
    #pragma unroll
    for (int kc = 0; kc < 4; ++kc){
      bf16x8 b = *(const bf16x8*)(wd1F + ((size_t)((nt*4+kc)*64 + l))*8);
      bf16x8 a = *(const bf16x8*)(mh + c15*136 + kc*32 + g8);
      acc = __builtin_amdgcn_mfma_f32_16x16x32_bf16(a, b, acc, 0,0,0);
    }
    int col = nt*16 + c15;
    float be = bd1E[col];
    #pragma unroll
    for (int reg = 0; reg < 4; ++reg){
      int row = ((l>>4)<<2) + reg;
      d1L[row*72 + col] = f2bf(fmaxf(acc[reg] + be, 0.f));
    }
  }
  __syncthreads();

  // S6: d2 = relu(d1 @ Wd2_eff^T + bd2E); waves 0,1 -> nt=w
  if (w < 2){
    const int nt = w;
    f32x4 acc = {0.f,0.f,0.f,0.f};
    #pragma unroll
    for (int kc = 0; kc < 2; ++kc){
      bf16x8 a = *(const bf16x8*)(d1L + c15*72 + kc*32 + g8);
      bf16x8 b = *(const bf16x8*)(wd2F + ((size_t)((nt*2+kc)*64 + l))*8);
      acc = __builtin_amdgcn_mfma_f32_16x16x32_bf16(a, b, acc, 0,0,0);
    }
    int col = nt*16 + c15;
    float be = bd2E[col];
    #pragma unroll
    for (int reg = 0; reg < 4; ++reg){
      int row = ((l>>4)<<2) + reg;
      d2L[row*40 + col] = f2bf(fmaxf(acc[reg] + be, 0.f));
    }
  }
  __syncthreads();

  // S7: out = d2 @ Wd3^T + bd3; waves 0,1 -> nt=w
  if (w < 2){
    const int nt = w;
    bf16x8 a = *(const bf16x8*)(d2L + c15*40 + g8);
    bf16x8 b = *(const bf16x8*)(wd3F + ((size_t)(nt*64 + l))*8);
    f32x4 acc = {0.f,0.f,0.f,0.f};
    acc = __builtin_amdgcn_mfma_f32_16x16x32_bf16(a, b, acc, 0,0,0);
    int col = nt*16 + c15;
    if (col < 20){
      float be = bd3[col];
      #pragma unroll
      for (int reg = 0; reg < 4; ++reg){
        int row = ((l>>4)<<2) + reg;
        out[(rowBase + row)*20 + col] = acc[reg] + be;
      }
    }
  }
}

// ---------------------------------------------------------------- launcher
extern "C" void kernel_launch(void* const* d_in, const int* in_sizes, int n_in,
                              void* d_out, int out_size, void* d_ws, size_t ws_size,
                              hipStream_t stream)
{
  (void)in_sizes; (void)n_in; (void)out_size; (void)ws_size;
  const float* x      = (const float*)d_in[0];
  const float* ln1_g  = (const float*)d_in[1];
  const float* ln1_b  = (const float*)d_in[2];
  const float* conv_w = (const float*)d_in[3];
  const float* conv_b = (const float*)d_in[4];
  const float* bn1_g  = (const float*)d_in[5];
  const float* bn1_b  = (const float*)d_in[6];
  const float* bn1_m  = (const float*)d_in[7];
  const float* bn1_v  = (const float*)d_in[8];
  const float* Q      = (const float*)d_in[9];
  const float* Wk     = (const float*)d_in[10];
  const float* bk     = (const float*)d_in[11];
  const float* W1     = (const float*)d_in[12];
  const float* b1     = (const float*)d_in[13];
  const float* bn2_g  = (const float*)d_in[14];
  const float* bn2_b  = (const float*)d_in[15];
  const float* bn2_m  = (const float*)d_in[16];
  const float* bn2_v  = (const float*)d_in[17];
  const float* oln_g  = (const float*)d_in[18];
  const float* oln_b  = (const float*)d_in[19];
  const float* Wd1    = (const float*)d_in[20];
  const float* bd1    = (const float*)d_in[21];
  const float* bnd1_g = (const float*)d_in[22];
  const float* bnd1_b = (const float*)d_in[23];
  const float* bnd1_m = (const float*)d_in[24];
  const float* bnd1_v = (const float*)d_in[25];
  const float* Wd2    = (const float*)d_in[26];
  const float* bd2    = (const float*)d_in[27];
  const float* bnd2_g = (const float*)d_in[28];
  const float* bnd2_b = (const float*)d_in[29];
  const float* bnd2_m = (const float*)d_in[30];
  const float* bnd2_v = (const float*)d_in[31];
  const float* Wd3    = (const float*)d_in[32];
  const float* bd3    = (const float*)d_in[33];

  char* ws = (char*)d_ws;
  unsigned short* wqF  = (unsigned short*)(ws + 0);        // 9216 B
  unsigned short* w1F  = (unsigned short*)(ws + 9216);     // 65536 B
  unsigned short* wd1F = (unsigned short*)(ws + 74752);    // 16384 B
  unsigned short* wd2F = (unsigned short*)(ws + 91136);    // 4096 B
  unsigned short* wd3F = (unsigned short*)(ws + 95232);    // 2048 B
  float* convwT = (float*)(ws + 97280);                    // 10240 B
  float* convbE = (float*)(ws + 107520);                   // 1024 B
  float* biasq  = (float*)(ws + 108544);                   // 64 B
  float* b1E    = (float*)(ws + 108608);                   // 512 B
  float* bd1E   = (float*)(ws + 109120);                   // 256 B
  float* bd2E   = (float*)(ws + 109376);                   // 128 B
  unsigned short* o_frag = (unsigned short*)(ws + 109568); // 8 MB

  hipLaunchKernelGGL(k0_pre, dim3(78), dim3(256), 0, stream,
      conv_w, conv_b, bn1_g, bn1_b, bn1_m, bn1_v, Q, Wk, bk,
      W1, b1, bn2_g, bn2_b, bn2_m, bn2_v, oln_g, oln_b,
      Wd1, bd1, bnd1_g, bnd1_b, bnd1_m, bnd1_v,
      Wd2, bd2, bnd2_g, bnd2_b, bnd2_m, bnd2_v, Wd3,
      wqF, w1F, wd1F, wd2F, wd3F, convwT, convbE, biasq, b1E, bd1E, bd2E);

  hipLaunchKernelGGL(k1_attn, dim3(8192), dim3(256), 0, stream,
      x, ln1_g, ln1_b, wqF, convwT, convbE, biasq, o_frag);

  hipLaunchKernelGGL(k2_mlp, dim3(1024), dim3(256), 0, stream,
      o_frag, w1F, b1E, wd1F, bd1E, wd2F, bd2E, wd3F, bd3, (float*)d_out);
}